// Round 2
// baseline (1610.222 us; speedup 1.0000x reference)
//
#include <hip/hip_runtime.h>

#define NEG_SLOPE 0.01f

// ---- order-preserving float<->uint mapping for atomicMax on floats ----
__device__ __forceinline__ unsigned float_to_ordered(float f) {
  unsigned u = __float_as_uint(f);
  return (u & 0x80000000u) ? ~u : (u | 0x80000000u);
}
__device__ __forceinline__ float ordered_to_float(unsigned k) {
  unsigned u = (k & 0x80000000u) ? (k & 0x7FFFFFFFu) : ~k;
  return __uint_as_float(u);
}

// ---- zero h_out region, amax keys, denom ----
__global__ void init_kernel(float* __restrict__ hout, unsigned* __restrict__ amax,
                            float* __restrict__ denom, int N) {
  const int gid = blockIdx.x * 256 + threadIdx.x;
  if (gid < N * 128) hout[gid] = 0.0f;
  if (gid < N * 4) { amax[gid] = 0u; denom[gid] = 0.0f; }
}

// ---- h_t = nfeats @ W_nodes + b_nodes  -> ws_ht [N,128] ----
__global__ __launch_bounds__(256) void node_kernel(
    const float* __restrict__ nfeats, const float* __restrict__ W_nodes,
    const float* __restrict__ b_nodes, float* __restrict__ ht, int N) {
  const int gid = blockIdx.x * 256 + threadIdx.x;
  if (gid >= N * 128) return;
  const int n = gid >> 7, c = gid & 127;
  float acc = b_nodes[c];
  const float* nrow = nfeats + n * 64;
#pragma unroll 8
  for (int k = 0; k < 64; ++k) acc += nrow[k] * W_nodes[k * 128 + c];
  ht[gid] = acc;
}

// ---- edge GEMM: f_out = leaky_relu(stack @ W_edges + b); a = f_out . w_sum ----
// Tile: 64 edges x 128 cols per block of 512 threads.
// Thread (tx=tid&31, ty=tid>>5): 4 edges (rows 4ty..4ty+3) x 4 cols (4tx..4tx+3).
__global__ __launch_bounds__(512) void edge_kernel(
    const float* __restrict__ nfeats, const float* __restrict__ efeats,
    const int* __restrict__ src, const int* __restrict__ dst,
    const float* __restrict__ W_edges, const float* __restrict__ b_edges,
    const float* __restrict__ W_attn,
    float* __restrict__ fout, float* __restrict__ a_out,
    unsigned* __restrict__ amax, int E) {
  __shared__ float s_stack[64 * 196];  // stride 196 breaks bank aliasing
  const int tid = threadIdx.x;
  const int e0 = blockIdx.x * 64;

  // stage [src(64)|efeats(64)|dst(64)] per edge row, float4 loads
  {
    const int row = tid >> 3;   // 0..63
    const int j = tid & 7;      // 0..7
    const int e = e0 + row;
    if (e < E) {
      const int se = src[e], de = dst[e];
      const float4* nf4 = (const float4*)nfeats;
      const float4* ef4 = (const float4*)efeats;
      float4* out4 = (float4*)(&s_stack[row * 196]);
#pragma unroll
      for (int i = 0; i < 6; ++i) {
        const int q = j + i * 8;  // 0..47
        float4 v;
        if (q < 16)      v = nf4[se * 16 + q];
        else if (q < 32) v = ef4[(size_t)e * 16 + (q - 16)];
        else             v = nf4[de * 16 + (q - 32)];
        out4[q] = v;
      }
    }
  }
  __syncthreads();

  const int tx = tid & 31;
  const int ty = tid >> 5;

  float4 acc[4];
#pragma unroll
  for (int i = 0; i < 4; ++i) acc[i] = make_float4(0.f, 0.f, 0.f, 0.f);

  const float4* W4 = (const float4*)W_edges;   // row k -> 32 float4
  const float* s_base = &s_stack[ty * 4 * 196];

#pragma unroll 4
  for (int k = 0; k < 192; ++k) {
    const float4 w = W4[k * 32 + tx];
    const float s0 = s_base[k];
    const float s1 = s_base[196 + k];
    const float s2 = s_base[392 + k];
    const float s3 = s_base[588 + k];
    acc[0].x += s0 * w.x; acc[0].y += s0 * w.y; acc[0].z += s0 * w.z; acc[0].w += s0 * w.w;
    acc[1].x += s1 * w.x; acc[1].y += s1 * w.y; acc[1].z += s1 * w.z; acc[1].w += s1 * w.w;
    acc[2].x += s2 * w.x; acc[2].y += s2 * w.y; acc[2].z += s2 * w.z; acc[2].w += s2 * w.w;
    acc[3].x += s3 * w.x; acc[3].y += s3 * w.y; acc[3].z += s3 * w.z; acc[3].w += s3 * w.w;
  }

  // epilogue: bias, leaky_relu, store f_out, attention logit reduce
  const float4 bias = ((const float4*)b_edges)[tx];
  const int cbase = 4 * tx;
  float wsum[4];
#pragma unroll
  for (int j = 0; j < 4; ++j) {
    const int f = (cbase + j) & 31;
    wsum[j] = W_attn[f * 4 + 0] + W_attn[f * 4 + 1] + W_attn[f * 4 + 2] + W_attn[f * 4 + 3];
  }
  const int head = tx >> 3;
  float4* fout4 = (float4*)fout;

#pragma unroll
  for (int ei = 0; ei < 4; ++ei) {
    const int e = e0 + ty * 4 + ei;
    float4 v = acc[ei];
    v.x += bias.x; v.y += bias.y; v.z += bias.z; v.w += bias.w;
    v.x = v.x >= 0.f ? v.x : NEG_SLOPE * v.x;
    v.y = v.y >= 0.f ? v.y : NEG_SLOPE * v.y;
    v.z = v.z >= 0.f ? v.z : NEG_SLOPE * v.z;
    v.w = v.w >= 0.f ? v.w : NEG_SLOPE * v.w;
    if (e < E) fout4[(size_t)e * 32 + tx] = v;
    float pa = v.x * wsum[0] + v.y * wsum[1] + v.z * wsum[2] + v.w * wsum[3];
    pa += __shfl_xor(pa, 1);
    pa += __shfl_xor(pa, 2);
    pa += __shfl_xor(pa, 4);
    if ((tx & 7) == 0 && e < E) {
      a_out[(size_t)e * 4 + head] = pa;
      atomicMax(&amax[(unsigned)dst[e] * 4u + head], float_to_ordered(pa));
    }
  }
}

// ---- a_exp = exp(a - amax[dst]); denom[dst] += a_exp ----
__global__ void softmax_kernel(const int* __restrict__ dst,
                               const unsigned* __restrict__ amax,
                               float* __restrict__ a, float* __restrict__ denom, int E) {
  const int gid = blockIdx.x * 256 + threadIdx.x;
  if (gid >= E * 4) return;
  const int e = gid >> 2, h = gid & 3;
  const int n = dst[e];
  const float m = ordered_to_float(amax[n * 4 + h]);
  const float ex = __expf(a[gid] - m);
  a[gid] = ex;
  atomicAdd(&denom[n * 4 + h], ex);
}

// ---- h_out[dst] += (a_exp/denom[dst]) * ht[src] ----
__global__ void scatter_kernel(const int* __restrict__ src, const int* __restrict__ dst,
                               const float* __restrict__ aexp, const float* __restrict__ denom,
                               const float* __restrict__ ht, float* __restrict__ hout, int E) {
  const int gid = blockIdx.x * 256 + threadIdx.x;
  if (gid >= E * 128) return;
  const int e = gid >> 7, c = gid & 127, h = c >> 5;
  const int sn = src[e], dn = dst[e];
  const float alpha = aexp[e * 4 + h] / denom[dn * 4 + h];
  atomicAdd(&hout[dn * 128 + c], alpha * ht[(size_t)sn * 128 + c]);
}

extern "C" void kernel_launch(void* const* d_in, const int* in_sizes, int n_in,
                              void* d_out, int out_size, void* d_ws, size_t ws_size,
                              hipStream_t stream) {
  const float* nfeats  = (const float*)d_in[0];
  const float* efeats  = (const float*)d_in[1];
  const int*   src     = (const int*)d_in[2];
  const int*   dst     = (const int*)d_in[3];
  const float* W_nodes = (const float*)d_in[4];
  const float* b_nodes = (const float*)d_in[5];
  const float* W_edges = (const float*)d_in[6];
  const float* b_edges = (const float*)d_in[7];
  const float* W_attn  = (const float*)d_in[8];

  const int N = in_sizes[0] / 64;
  const int E = in_sizes[2];

  // workspace layout (floats): ht[N*128] | a[E*4] | amax[N*4] | denom[N*4]
  float* ws = (float*)d_ws;
  float* ht = ws;
  float* a  = ws + (size_t)N * 128;
  unsigned* amax = (unsigned*)(a + (size_t)E * 4);
  float* denom = (float*)(amax + (size_t)N * 4);

  float* hout = (float*)d_out;                    // [N,4,32]
  float* fout = hout + (size_t)N * 128;           // [E,4,32]

  const int nh_threads = N * 128;
  init_kernel<<<(nh_threads + 255) / 256, 256, 0, stream>>>(hout, amax, denom, N);
  node_kernel<<<(nh_threads + 255) / 256, 256, 0, stream>>>(nfeats, W_nodes, b_nodes, ht, N);
  edge_kernel<<<(E + 63) / 64, 512, 0, stream>>>(nfeats, efeats, src, dst, W_edges,
                                                 b_edges, W_attn, fout, a, amax, E);
  softmax_kernel<<<(E * 4 + 255) / 256, 256, 0, stream>>>(dst, amax, a, denom, E);
  scatter_kernel<<<((size_t)E * 128 + 255) / 256, 256, 0, stream>>>(src, dst, a, denom, ht, hout, E);
}